// Round 6
// baseline (191.224 us; speedup 1.0000x reference)
//
#include <hip/hip_runtime.h>
#include <hip/hip_bf16.h>
#include <math.h>

#define B_ 8
#define T_ 2048
#define C_ 1024
#define H_ 64
#define M_ (B_*T_)      // 16384

typedef __attribute__((ext_vector_type(8))) short short8;
typedef __attribute__((ext_vector_type(4))) float f32x4;
typedef unsigned int u32;

__device__ __forceinline__ unsigned short f2bf(float f) {
    u32 u = __builtin_bit_cast(u32, f);
    u += 0x7FFFu + ((u >> 16) & 1u);      // RNE
    return (unsigned short)(u >> 16);
}

__device__ __forceinline__ void gl2lds16(const void* g, void* l) {
    __builtin_amdgcn_global_load_lds(
        (const __attribute__((address_space(1))) u32*)g,
        (__attribute__((address_space(3))) u32*)l, 16, 0, 0);
}

// ---------------- Kernel 0: W -> bf16, transposed [n][k], q-scaled, XOR-swizzled ----------------
__global__ __launch_bounds__(256) void wconv(
    const float* __restrict__ Wk, const float* __restrict__ Wq,
    const float* __restrict__ Wv, unsigned short* __restrict__ wb)
{
    __shared__ unsigned short lt[64][64];          // [n][k_local]
    const int mat = blockIdx.x >> 4;               // 0:k 1:q 2:v
    const int k0  = (blockIdx.x & 15) * 64;
    const float* src = (mat == 0) ? Wk : (mat == 1 ? Wq : Wv);
    const float sc = (mat == 1) ? 0.03125f : 1.0f; // fold C^-0.5 into q
    const int tid = threadIdx.x;

    for (int it = 0; it < 16; ++it) {
        int idx = it * 256 + tid;                  // 0..4095
        int r = idx >> 6, cn = idx & 63;           // r=k_local, cn=n_local
        lt[cn][r] = f2bf(src[(size_t)(k0 + r) * H_ + cn] * sc);
    }
    __syncthreads();
    for (int g = 0; g < 2; ++g) {
        int n  = g * 32 + (tid >> 3);
        int kp = tid & 7;
        int ng = mat * 64 + n;
        short8 v = *reinterpret_cast<const short8*>(&lt[n][kp * 8]);
        char* dst = (char*)wb + (size_t)ng * 2048 + (k0 >> 6) * 128
                  + ((kp * 16) ^ ((ng & 7) << 4));
        *reinterpret_cast<short8*>(dst) = v;
    }
}

// ---------------- Kernel 1: QKV GEMM (unchanged from round 5) ----------------
__global__ __launch_bounds__(256, 2) void qkv_mm(
    const float* __restrict__ x, const unsigned short* __restrict__ wb,
    unsigned short* __restrict__ kb, unsigned short* __restrict__ qb,
    unsigned short* __restrict__ vT)
{
    __shared__ __align__(16) unsigned short Ws[2][96 * 64];   // 24 KB

    const int tid  = threadIdx.x;
    const int wid  = tid >> 6;
    const int lane = tid & 63;
    const int lr   = lane & 15;
    const int lg   = lane >> 4;
    const int mt   = blockIdx.x >> 1;
    const int bn   = blockIdx.x & 1;
    const int m0   = mt * 64;
    const int n0   = bn * 96;

    const float* xrow = x + (size_t)(m0 + wid * 16 + lr) * C_ + lg * 8;

    f32x4 acc[6];
    for (int c = 0; c < 6; ++c) acc[c] = (f32x4){0.f, 0.f, 0.f, 0.f};

    float4 xa = *reinterpret_cast<const float4*>(xrow);
    float4 xb2 = *reinterpret_cast<const float4*>(xrow + 4);
    float4 xc = *reinterpret_cast<const float4*>(xrow + 32);
    float4 xd = *reinterpret_cast<const float4*>(xrow + 36);
    for (int p = 0; p < 3; ++p) {
        int c = p * 256 + tid;                    // 0..767
        gl2lds16((const char*)wb + (size_t)(n0 + (c >> 3)) * 2048 + (c & 7) * 16,
                 (char*)&Ws[0][0] + c * 16);
    }

    for (int t = 0; t < 16; ++t) {
        __syncthreads();
        float4 na, nb, nc, nd;
        if (t < 15) {
            const float* xn = xrow + (t + 1) * 64;
            na = *reinterpret_cast<const float4*>(xn);
            nb = *reinterpret_cast<const float4*>(xn + 4);
            nc = *reinterpret_cast<const float4*>(xn + 32);
            nd = *reinterpret_cast<const float4*>(xn + 36);
            int buf = (t + 1) & 1;
            for (int p = 0; p < 3; ++p) {
                int c = p * 256 + tid;
                gl2lds16((const char*)wb + (size_t)(n0 + (c >> 3)) * 2048
                             + (size_t)(t + 1) * 128 + (c & 7) * 16,
                         (char*)&Ws[buf][0] + c * 16);
            }
        }

        short8 af0, af1;
        af0[0] = (short)f2bf(xa.x); af0[1] = (short)f2bf(xa.y);
        af0[2] = (short)f2bf(xa.z); af0[3] = (short)f2bf(xa.w);
        af0[4] = (short)f2bf(xb2.x); af0[5] = (short)f2bf(xb2.y);
        af0[6] = (short)f2bf(xb2.z); af0[7] = (short)f2bf(xb2.w);
        af1[0] = (short)f2bf(xc.x); af1[1] = (short)f2bf(xc.y);
        af1[2] = (short)f2bf(xc.z); af1[3] = (short)f2bf(xc.w);
        af1[4] = (short)f2bf(xd.x); af1[5] = (short)f2bf(xd.y);
        af1[6] = (short)f2bf(xd.z); af1[7] = (short)f2bf(xd.w);

        const char* wbuf = (const char*)&Ws[t & 1][0];
        #pragma unroll
        for (int kc = 0; kc < 2; ++kc) {
            short8 afc = kc ? af1 : af0;
            #pragma unroll
            for (int ct = 0; ct < 6; ++ct) {
                int n = ct * 16 + lr;
                short8 bf = *reinterpret_cast<const short8*>(
                    wbuf + n * 128 + ((kc * 64 + lg * 16) ^ ((n & 7) << 4)));
                acc[ct] = __builtin_amdgcn_mfma_f32_16x16x32_bf16(afc, bf, acc[ct], 0, 0, 0);
            }
        }
        xa = na; xb2 = nb; xc = nc; xd = nd;
    }

    for (int ct = 0; ct < 6; ++ct) {
        int ng = n0 + ct * 16 + lr;
        int col = ng & 63;
        for (int i = 0; i < 4; ++i) {
            int m = m0 + wid * 16 + lg * 4 + i;
            unsigned short val = f2bf(acc[ct][i]);
            if (ng < 64)       kb[(size_t)m * H_ + col] = val;
            else if (ng < 128) qb[(size_t)m * H_ + col] = val;
            else               vT[((size_t)(m >> 11) * H_ + col) * T_ + (m & (T_ - 1))] = val;
        }
    }
}

// ---------------- Kernel 2: flash attention, per-wave LDS pipeline ----------------
// 4 independent waves per block (split-KV over one 16-row q-tile). Each wave:
// private LDS slice {K dbuf 2x8KB, V 8KB}, global_load_lds staging, counted
// vmcnt(8) waits, XOR-swizzled (source-preswizzled) tiles. No main-loop barriers.
__global__ __launch_bounds__(256) void attn6(
    const unsigned short* __restrict__ kb,
    const unsigned short* __restrict__ qb,
    const unsigned short* __restrict__ vT,
    float* __restrict__ out)
{
    __shared__ __align__(16) char kvbuf[4][24576];   // per wave: K[2][8192] | V[8192]
    __shared__ __align__(16) unsigned short Ps[4][16][72];
    __shared__ float Mv[4][16], Lv[4][16], Fac[4][16], InvL[16];

    const int tid  = threadIdx.x;
    const int wid  = tid >> 6;
    const int lane = tid & 63;
    const int lr   = lane & 15;
    const int lg   = lane >> 4;
    const int b    = blockIdx.y;
    const int bx   = blockIdx.x;
    const int tile = (bx & 1) ? (127 - (bx >> 1)) : (bx >> 1);  // mix big+small
    const int q0   = tile * 16;
    const int nst  = (tile >> 2) + 1;                 // kv steps of 64
    const size_t base = (size_t)b * T_ * H_;
    const char* kbyte = (const char*)(kb + base);
    const char* vbyte = (const char*)(vT + (size_t)b * H_ * T_);
    char* slice = kvbuf[wid];

    short8 qf[2];
    #pragma unroll
    for (int kc = 0; kc < 2; ++kc)
        qf[kc] = *reinterpret_cast<const short8*>(
            qb + base + (size_t)(q0 + lr) * H_ + kc * 32 + lg * 8);

    f32x4 o[4];
    float mrun[4], lrun[4];
    for (int dt = 0; dt < 4; ++dt) o[dt] = (f32x4){0.f, 0.f, 0.f, 0.f};
    for (int i = 0; i < 4; ++i) { mrun[i] = -INFINITY; lrun[i] = 0.f; }

    // stage K tile (8KB): source-preswizzled so swizzled ds_reads see linear content
    auto stageK = [&](int buf, int kv0) {
        const char* ks = kbyte + kv0 * 128;
        char* dst = slice + buf * 8192;
        #pragma unroll
        for (int i = 0; i < 8; ++i) {
            int c = i * 64 + lane;
            int row = c >> 3, colB = (c & 7) * 16;
            gl2lds16(ks + row * 128 + (colB ^ ((row & 7) << 4)), dst + c * 16);
        }
    };
    auto stageV = [&](int kv0) {
        const char* vs = vbyte + kv0 * 2;
        char* dst = slice + 16384;
        #pragma unroll
        for (int i = 0; i < 8; ++i) {
            int c = i * 64 + lane;
            int row = c >> 3, colB = (c & 7) * 16;
            gl2lds16(vs + (size_t)row * 4096 + (colB ^ ((row & 7) << 4)), dst + c * 16);
        }
    };

    int s = wid, cur = 0;
    if (s < nst) { stageK(0, s * 64); stageV(s * 64); }

    for (; s < nst; s += 4) {
        const int kv0 = s * 64;
        const bool more = (s + 4) < nst;

        asm volatile("s_waitcnt vmcnt(8)" ::: "memory");   // K(s) ready (V may lag)
        __builtin_amdgcn_sched_barrier(0);
        if (more) stageK(cur ^ 1, kv0 + 256);              // in flight under compute

        // S = Q K^T from swizzled K tile
        const char* kt_base = slice + cur * 8192;
        f32x4 sv4[4];
        #pragma unroll
        for (int kt = 0; kt < 4; ++kt) sv4[kt] = (f32x4){0.f, 0.f, 0.f, 0.f};
        #pragma unroll
        for (int kc = 0; kc < 2; ++kc) {
            #pragma unroll
            for (int kt = 0; kt < 4; ++kt) {
                int row = kt * 16 + lr;
                short8 kf = *reinterpret_cast<const short8*>(
                    kt_base + row * 128 + ((kc * 64 + lg * 16) ^ ((row & 7) << 4)));
                sv4[kt] = __builtin_amdgcn_mfma_f32_16x16x32_bf16(qf[kc], kf, sv4[kt], 0, 0, 0);
            }
        }

        const bool need_mask = (s == nst - 1);   // only diagonal tile masks
        #pragma unroll
        for (int i = 0; i < 4; ++i) {
            int row = q0 + lg * 4 + i;
            float sv[4];
            float mx = -INFINITY;
            if (need_mask) {
                #pragma unroll
                for (int kt = 0; kt < 4; ++kt) {
                    int key = kv0 + kt * 16 + lr;
                    float v = (key <= row) ? sv4[kt][i] : -INFINITY;
                    sv[kt] = v;
                    mx = fmaxf(mx, v);
                }
            } else {
                #pragma unroll
                for (int kt = 0; kt < 4; ++kt) {
                    sv[kt] = sv4[kt][i];
                    mx = fmaxf(mx, sv[kt]);
                }
            }
            for (int d = 8; d; d >>= 1) mx = fmaxf(mx, __shfl_xor(mx, d));
            float mn  = fmaxf(mrun[i], mx);
            float fac = __expf(mrun[i] - mn);
            float rs  = 0.f;
            #pragma unroll
            for (int kt = 0; kt < 4; ++kt) {
                float p = __expf(sv[kt] - mn);
                rs += p;
                Ps[wid][lg * 4 + i][kt * 16 + lr] = f2bf(p);
            }
            for (int d = 8; d; d >>= 1) rs += __shfl_xor(rs, d);
            lrun[i] = lrun[i] * fac + rs;
            mrun[i] = mn;
            #pragma unroll
            for (int dt = 0; dt < 4; ++dt)
                o[dt][i] *= fac;
        }

        asm volatile("s_waitcnt vmcnt(8)" ::: "memory");   // V(s) ready (K(s+4) may lag)
        __builtin_amdgcn_sched_barrier(0);

        // O += P * V from swizzled V tile
        const char* vt_base = slice + 16384;
        #pragma unroll
        for (int kc = 0; kc < 2; ++kc) {
            short8 pf = *reinterpret_cast<const short8*>(&Ps[wid][lr][kc * 32 + lg * 8]);
            #pragma unroll
            for (int dt = 0; dt < 4; ++dt) {
                int row = dt * 16 + lr;
                short8 vf = *reinterpret_cast<const short8*>(
                    vt_base + row * 128 + ((kc * 64 + lg * 16) ^ ((row & 7) << 4)));
                o[dt] = __builtin_amdgcn_mfma_f32_16x16x32_bf16(pf, vf, o[dt], 0, 0, 0);
            }
        }

        __builtin_amdgcn_sched_barrier(0);
        if (more) stageV(kv0 + 256);      // V single-buffer: overwrite after PV reads
        cur ^= 1;
    }

    // ---- merge the 4 per-wave partial states (Om aliased onto kvbuf) ----
    __syncthreads();
    float (*Om)[16][64] = (float (*)[16][64])kvbuf;
    for (int dt = 0; dt < 4; ++dt)
        for (int i = 0; i < 4; ++i)
            Om[wid][lg * 4 + i][dt * 16 + lr] = o[dt][i];
    if (lr == 0)
        for (int i = 0; i < 4; ++i) {
            Mv[wid][lg * 4 + i] = mrun[i];
            Lv[wid][lg * 4 + i] = lrun[i];
        }
    __syncthreads();
    if (tid < 16) {
        float M = Mv[0][tid];
        for (int w = 1; w < 4; ++w) M = fmaxf(M, Mv[w][tid]);
        float L = 0.f;
        for (int w = 0; w < 4; ++w) {
            float f = __expf(Mv[w][tid] - M);
            Fac[w][tid] = f;
            L += Lv[w][tid] * f;
        }
        InvL[tid] = 1.0f / L;
    }
    __syncthreads();
    for (int e = 0; e < 4; ++e) {
        int idx = e * 256 + tid;
        int row = idx >> 6, d = idx & 63;
        float v = 0.f;
        for (int w = 0; w < 4; ++w) v += Om[w][row][d] * Fac[w][row];
        out[base + (size_t)(q0 + row) * H_ + d] = v * InvL[row];
    }
}

extern "C" void kernel_launch(void* const* d_in, const int* in_sizes, int n_in,
                              void* d_out, int out_size, void* d_ws, size_t ws_size,
                              hipStream_t stream) {
    const float* x  = (const float*)d_in[0];
    const float* Wk = (const float*)d_in[1];
    const float* Wq = (const float*)d_in[2];
    const float* Wv = (const float*)d_in[3];
    float* out = (float*)d_out;

    unsigned short* kb = (unsigned short*)d_ws;              // 1 M elems
    unsigned short* qb = kb + (size_t)M_ * H_;               // 1 M elems
    unsigned short* vT = qb + (size_t)M_ * H_;               // 1 M elems ([b][d][t])
    unsigned short* wb = vT + (size_t)M_ * H_;               // 192*1024 elems

    wconv<<<48, 256, 0, stream>>>(Wk, Wq, Wv, wb);
    qkv_mm<<<512, 256, 0, stream>>>(x, wb, kb, qb, vT);
    attn6<<<dim3(128, B_), 256, 0, stream>>>(kb, qb, vT, out);
}

// Round 7
// 162.817 us; speedup vs baseline: 1.1745x; 1.1745x over previous
//
#include <hip/hip_runtime.h>
#include <hip/hip_bf16.h>
#include <math.h>

#define B_ 8
#define T_ 2048
#define C_ 1024
#define H_ 64
#define M_ (B_*T_)      // 16384

typedef __attribute__((ext_vector_type(8))) short short8;
typedef __attribute__((ext_vector_type(4))) float f32x4;
typedef unsigned int u32;

__device__ __forceinline__ unsigned short f2bf(float f) {
    u32 u = __builtin_bit_cast(u32, f);
    u += 0x7FFFu + ((u >> 16) & 1u);      // RNE
    return (unsigned short)(u >> 16);
}
__device__ __forceinline__ float bf2f(unsigned short h) {
    u32 u = ((u32)h) << 16;
    return __builtin_bit_cast(float, u);
}

__device__ __forceinline__ void gl2lds16(const void* g, void* l) {
    __builtin_amdgcn_global_load_lds(
        (const __attribute__((address_space(1))) u32*)g,
        (__attribute__((address_space(3))) u32*)l, 16, 0, 0);
}

// ---------------- Kernel 0: W -> bf16, transposed [n][k], q-scaled, XOR-swizzled ----------------
__global__ __launch_bounds__(256) void wconv(
    const float* __restrict__ Wk, const float* __restrict__ Wq,
    const float* __restrict__ Wv, unsigned short* __restrict__ wb)
{
    __shared__ unsigned short lt[64][64];          // [n][k_local]
    const int mat = blockIdx.x >> 4;               // 0:k 1:q 2:v
    const int k0  = (blockIdx.x & 15) * 64;
    const float* src = (mat == 0) ? Wk : (mat == 1 ? Wq : Wv);
    const float sc = (mat == 1) ? 0.03125f : 1.0f; // fold C^-0.5 into q
    const int tid = threadIdx.x;

    for (int it = 0; it < 16; ++it) {
        int idx = it * 256 + tid;                  // 0..4095
        int r = idx >> 6, cn = idx & 63;           // r=k_local, cn=n_local
        lt[cn][r] = f2bf(src[(size_t)(k0 + r) * H_ + cn] * sc);
    }
    __syncthreads();
    for (int g = 0; g < 2; ++g) {
        int n  = g * 32 + (tid >> 3);
        int kp = tid & 7;
        int ng = mat * 64 + n;
        short8 v = *reinterpret_cast<const short8*>(&lt[n][kp * 8]);
        char* dst = (char*)wb + (size_t)ng * 2048 + (k0 >> 6) * 128
                  + ((kp * 16) ^ ((ng & 7) << 4));
        *reinterpret_cast<short8*>(dst) = v;
    }
}

// ---------------- Kernel 1: QKV GEMM, BN=192, X read once ----------------
// 256 blocks (1/CU), 4 waves x 16 rows. W 24KB/step dbuf via global_load_lds;
// X triple-buffered loop-carried regs (prefetch t+2). Raw s_barrier with
// counted vmcnt(4): X(t+2) loads stay in flight across the barrier.
#define LOADX(R0,R1,R2,R3,t) {                                        \
    const float* p_ = xrow + (t) * 64;                                \
    R0 = *reinterpret_cast<const float4*>(p_);                        \
    R1 = *reinterpret_cast<const float4*>(p_ + 4);                    \
    R2 = *reinterpret_cast<const float4*>(p_ + 32);                   \
    R3 = *reinterpret_cast<const float4*>(p_ + 36); }

#define STAGEW(buf, t) {                                              \
    _Pragma("unroll") for (int p_ = 0; p_ < 6; ++p_) {                \
        int c_ = p_ * 256 + tid;                                      \
        gl2lds16((const char*)wb + (size_t)(c_ >> 3) * 2048           \
                     + (size_t)(t) * 128 + (c_ & 7) * 16,             \
                 (char*)&Ws[buf][0] + c_ * 16);                       \
    } }

__global__ __launch_bounds__(256) void qkv_mm(
    const float* __restrict__ x, const unsigned short* __restrict__ wb,
    unsigned short* __restrict__ kb, unsigned short* __restrict__ qb,
    unsigned short* __restrict__ vT)
{
    __shared__ __align__(16) unsigned short Ws[2][192 * 64];   // 48 KB

    const int tid  = threadIdx.x;
    const int wid  = tid >> 6;
    const int lane = tid & 63;
    const int lr   = lane & 15;
    const int lg   = lane >> 4;
    const int m0   = blockIdx.x * 64;

    const float* xrow = x + (size_t)(m0 + wid * 16 + lr) * C_ + lg * 8;

    f32x4 acc[12];
    #pragma unroll
    for (int c = 0; c < 12; ++c) acc[c] = (f32x4){0.f, 0.f, 0.f, 0.f};

    float4 xA0, xA1, xA2, xA3, xB0, xB1, xB2, xB3, xC0, xC1, xC2, xC3;

    LOADX(xA0, xA1, xA2, xA3, 0);
    __builtin_amdgcn_sched_barrier(0);
    STAGEW(0, 0);
    __builtin_amdgcn_sched_barrier(0);
    LOADX(xB0, xB1, xB2, xB3, 1);
    __builtin_amdgcn_sched_barrier(0);

    #pragma unroll
    for (int t = 0; t < 16; ++t) {
        // need X(t), W(t) done; X(t+1) (last 4 issued) may stay in flight
        if (t < 15) asm volatile("s_waitcnt vmcnt(4) lgkmcnt(0)" ::: "memory");
        else        asm volatile("s_waitcnt vmcnt(0) lgkmcnt(0)" ::: "memory");
        __builtin_amdgcn_s_barrier();
        __builtin_amdgcn_sched_barrier(0);
        if (t < 15) { STAGEW((t + 1) & 1, t + 1); }
        __builtin_amdgcn_sched_barrier(0);
        if (t < 14) { LOADX(xC0, xC1, xC2, xC3, t + 2); }
        __builtin_amdgcn_sched_barrier(0);

        short8 af0, af1;
        af0[0] = (short)f2bf(xA0.x); af0[1] = (short)f2bf(xA0.y);
        af0[2] = (short)f2bf(xA0.z); af0[3] = (short)f2bf(xA0.w);
        af0[4] = (short)f2bf(xA1.x); af0[5] = (short)f2bf(xA1.y);
        af0[6] = (short)f2bf(xA1.z); af0[7] = (short)f2bf(xA1.w);
        af1[0] = (short)f2bf(xA2.x); af1[1] = (short)f2bf(xA2.y);
        af1[2] = (short)f2bf(xA2.z); af1[3] = (short)f2bf(xA2.w);
        af1[4] = (short)f2bf(xA3.x); af1[5] = (short)f2bf(xA3.y);
        af1[6] = (short)f2bf(xA3.z); af1[7] = (short)f2bf(xA3.w);

        const char* wbuf = (const char*)&Ws[t & 1][0];
        #pragma unroll
        for (int kc = 0; kc < 2; ++kc) {
            short8 afc = kc ? af1 : af0;
            #pragma unroll
            for (int ct = 0; ct < 12; ++ct) {
                int n = ct * 16 + lr;
                short8 bf = *reinterpret_cast<const short8*>(
                    wbuf + n * 128 + ((kc * 64 + lg * 16) ^ ((n & 7) << 4)));
                acc[ct] = __builtin_amdgcn_mfma_f32_16x16x32_bf16(afc, bf, acc[ct], 0, 0, 0);
            }
        }
        xA0 = xB0; xA1 = xB1; xA2 = xB2; xA3 = xB3;
        xB0 = xC0; xB1 = xC1; xB2 = xC2; xB3 = xC3;
    }

    // epilogue: D layout col=lane&15, row=(lane>>4)*4+reg
    #pragma unroll
    for (int ct = 0; ct < 12; ++ct) {
        int n = ct * 16 + lr;
        int col = n & 63;
        #pragma unroll
        for (int i = 0; i < 4; ++i) {
            int m = m0 + wid * 16 + lg * 4 + i;
            unsigned short val = f2bf(acc[ct][i]);
            if (n < 64)       kb[(size_t)m * H_ + col] = val;
            else if (n < 128) qb[(size_t)m * H_ + col] = val;
            else              vT[((size_t)(m >> 11) * H_ + col) * T_ + (m & (T_ - 1))] = val;
        }
    }
}

// ---------------- Kernel 2: flash attention, 1-wave blocks, global split-KV ----------------
// grid (4 splits, 128 tiles, 8 batches) = 4096 waves = 4 waves/SIMD resident.
// Each wave: one 16-row q-tile, kv steps s0, s0+4, ... ; writes bf16 O-partial + (m,l).
__global__ __launch_bounds__(64) void attn7(
    const unsigned short* __restrict__ kb,
    const unsigned short* __restrict__ qb,
    const unsigned short* __restrict__ vT,
    unsigned short* __restrict__ opart,
    float* __restrict__ ml)
{
    __shared__ __align__(16) unsigned short Ps[16][72];

    const int lane = threadIdx.x;
    const int lr   = lane & 15;
    const int lg   = lane >> 4;
    const int s0   = blockIdx.x;
    const int tile = 127 - blockIdx.y;          // big tiles dispatched first
    const int b    = blockIdx.z;
    const int q0   = tile * 16;
    const int nst  = (tile >> 2) + 1;
    const size_t base = (size_t)b * T_ * H_;
    const unsigned short* vTb = vT + (size_t)b * H_ * T_;

    short8 qf[2];
    #pragma unroll
    for (int kc = 0; kc < 2; ++kc)
        qf[kc] = *reinterpret_cast<const short8*>(
            qb + base + (size_t)(q0 + lr) * H_ + kc * 32 + lg * 8);

    f32x4 o[4];
    float mrun[4], lrun[4];
    for (int dt = 0; dt < 4; ++dt) o[dt] = (f32x4){0.f, 0.f, 0.f, 0.f};
    for (int i = 0; i < 4; ++i) { mrun[i] = -INFINITY; lrun[i] = 0.f; }

    for (int s = s0; s < nst; s += 4) {
        const int kv0 = s * 64;

        // S = Q K^T, K frags direct from L2
        f32x4 sv4[4];
        #pragma unroll
        for (int kt = 0; kt < 4; ++kt) sv4[kt] = (f32x4){0.f, 0.f, 0.f, 0.f};
        #pragma unroll
        for (int kc = 0; kc < 2; ++kc) {
            #pragma unroll
            for (int kt = 0; kt < 4; ++kt) {
                short8 kf = *reinterpret_cast<const short8*>(
                    kb + base + (size_t)(kv0 + kt * 16 + lr) * H_ + kc * 32 + lg * 8);
                sv4[kt] = __builtin_amdgcn_mfma_f32_16x16x32_bf16(qf[kc], kf, sv4[kt], 0, 0, 0);
            }
        }

        const bool need_mask = (s == nst - 1);   // only diagonal tile masks
        #pragma unroll
        for (int i = 0; i < 4; ++i) {
            int row = q0 + lg * 4 + i;
            float sv[4];
            float mx = -INFINITY;
            if (need_mask) {
                #pragma unroll
                for (int kt = 0; kt < 4; ++kt) {
                    int key = kv0 + kt * 16 + lr;
                    float v = (key <= row) ? sv4[kt][i] : -INFINITY;
                    sv[kt] = v;
                    mx = fmaxf(mx, v);
                }
            } else {
                #pragma unroll
                for (int kt = 0; kt < 4; ++kt) {
                    sv[kt] = sv4[kt][i];
                    mx = fmaxf(mx, sv[kt]);
                }
            }
            for (int d = 8; d; d >>= 1) mx = fmaxf(mx, __shfl_xor(mx, d));
            float mn  = fmaxf(mrun[i], mx);
            float fac = __expf(mrun[i] - mn);
            float rs  = 0.f;
            #pragma unroll
            for (int kt = 0; kt < 4; ++kt) {
                float p = __expf(sv[kt] - mn);
                rs += p;
                Ps[lg * 4 + i][kt * 16 + lr] = f2bf(p);
            }
            for (int d = 8; d; d >>= 1) rs += __shfl_xor(rs, d);
            lrun[i] = lrun[i] * fac + rs;
            mrun[i] = mn;
            #pragma unroll
            for (int dt = 0; dt < 4; ++dt)
                o[dt][i] *= fac;
        }

        // O += P * V, V^T frags contiguous 16B
        #pragma unroll
        for (int kc = 0; kc < 2; ++kc) {
            short8 pf = *reinterpret_cast<const short8*>(&Ps[lr][kc * 32 + lg * 8]);
            #pragma unroll
            for (int dt = 0; dt < 4; ++dt) {
                short8 vf = *reinterpret_cast<const short8*>(
                    vTb + (size_t)(dt * 16 + lr) * T_ + kv0 + kc * 32 + lg * 8);
                o[dt] = __builtin_amdgcn_mfma_f32_16x16x32_bf16(pf, vf, o[dt], 0, 0, 0);
            }
        }
    }

    // write partials (always — merge kernel reads all 4 splits)
    unsigned short* op = opart + ((size_t)s0 * M_ + (size_t)b * T_ + q0) * H_;
    #pragma unroll
    for (int i = 0; i < 4; ++i)
        #pragma unroll
        for (int dt = 0; dt < 4; ++dt)
            op[(size_t)(lg * 4 + i) * H_ + dt * 16 + lr] = f2bf(o[dt][i]);
    if (lr == 0) {
        float* mlp = ml + ((size_t)s0 * M_ + (size_t)b * T_ + q0) * 2;
        #pragma unroll
        for (int i = 0; i < 4; ++i) {
            mlp[(lg * 4 + i) * 2 + 0] = mrun[i];
            mlp[(lg * 4 + i) * 2 + 1] = lrun[i];
        }
    }
}

// ---------------- Kernel 3: merge 4 split-KV partials ----------------
__global__ __launch_bounds__(256) void attn_merge(
    const unsigned short* __restrict__ opart,
    const float* __restrict__ ml,
    float* __restrict__ out)
{
    const int idx = blockIdx.x * 256 + threadIdx.x;   // 0..1048575
    const int row = idx >> 6;
    const int col = idx & 63;

    float mv[4], lv[4];
    float M = -INFINITY;
    #pragma unroll
    for (int s = 0; s < 4; ++s) {
        mv[s] = ml[((size_t)s * M_ + row) * 2 + 0];
        lv[s] = ml[((size_t)s * M_ + row) * 2 + 1];
        M = fmaxf(M, mv[s]);
    }
    float L = 0.f, acc = 0.f;
    #pragma unroll
    for (int s = 0; s < 4; ++s) {
        float fac = __expf(mv[s] - M);
        L += lv[s] * fac;
        acc += bf2f(opart[(size_t)s * M_ * H_ + (size_t)row * H_ + col]) * fac;
    }
    out[idx] = acc / L;
}

extern "C" void kernel_launch(void* const* d_in, const int* in_sizes, int n_in,
                              void* d_out, int out_size, void* d_ws, size_t ws_size,
                              hipStream_t stream) {
    const float* x  = (const float*)d_in[0];
    const float* Wk = (const float*)d_in[1];
    const float* Wq = (const float*)d_in[2];
    const float* Wv = (const float*)d_in[3];
    float* out = (float*)d_out;

    unsigned short* kb    = (unsigned short*)d_ws;           // 1 M elems (2 MB)
    unsigned short* qb    = kb + (size_t)M_ * H_;            // 2 MB
    unsigned short* vT    = qb + (size_t)M_ * H_;            // 2 MB ([b][d][t])
    unsigned short* wb    = vT + (size_t)M_ * H_;            // 384 KB
    unsigned short* opart = wb + (size_t)192 * C_;           // 4*16384*64 bf16 = 8 MB
    float*          ml    = (float*)(opart + (size_t)4 * M_ * H_);  // 512 KB

    wconv<<<48, 256, 0, stream>>>(Wk, Wq, Wv, wb);
    qkv_mm<<<256, 256, 0, stream>>>(x, wb, kb, qb, vT);
    attn7<<<dim3(4, 128, B_), 64, 0, stream>>>(kb, qb, vT, opart, ml);
    attn_merge<<<M_ * H_ / 256, 256, 0, stream>>>(opart, ml, out);
}

// Round 8
// 155.771 us; speedup vs baseline: 1.2276x; 1.0452x over previous
//
#include <hip/hip_runtime.h>
#include <hip/hip_bf16.h>
#include <math.h>

#define B_ 8
#define T_ 2048
#define C_ 1024
#define H_ 64
#define M_ (B_*T_)      // 16384

typedef __attribute__((ext_vector_type(8))) short short8;
typedef __attribute__((ext_vector_type(4))) float f32x4;
typedef unsigned int u32;

__device__ __forceinline__ unsigned short f2bf(float f) {
    u32 u = __builtin_bit_cast(u32, f);
    u += 0x7FFFu + ((u >> 16) & 1u);      // RNE
    return (unsigned short)(u >> 16);
}
__device__ __forceinline__ float bf2f(unsigned short h) {
    u32 u = ((u32)h) << 16;
    return __builtin_bit_cast(float, u);
}

__device__ __forceinline__ void gl2lds16(const void* g, void* l) {
    __builtin_amdgcn_global_load_lds(
        (const __attribute__((address_space(1))) u32*)g,
        (__attribute__((address_space(3))) u32*)l, 16, 0, 0);
}

// ---------------- Kernel 0: W -> bf16, transposed [n][k], q-scaled, XOR-swizzled ----------------
__global__ __launch_bounds__(256) void wconv(
    const float* __restrict__ Wk, const float* __restrict__ Wq,
    const float* __restrict__ Wv, unsigned short* __restrict__ wb)
{
    __shared__ unsigned short lt[64][64];          // [n][k_local]
    const int mat = blockIdx.x >> 4;               // 0:k 1:q 2:v
    const int k0  = (blockIdx.x & 15) * 64;
    const float* src = (mat == 0) ? Wk : (mat == 1 ? Wq : Wv);
    const float sc = (mat == 1) ? 0.03125f : 1.0f; // fold C^-0.5 into q
    const int tid = threadIdx.x;

    for (int it = 0; it < 16; ++it) {
        int idx = it * 256 + tid;                  // 0..4095
        int r = idx >> 6, cn = idx & 63;           // r=k_local, cn=n_local
        lt[cn][r] = f2bf(src[(size_t)(k0 + r) * H_ + cn] * sc);
    }
    __syncthreads();
    for (int g = 0; g < 2; ++g) {
        int n  = g * 32 + (tid >> 3);
        int kp = tid & 7;
        int ng = mat * 64 + n;
        short8 v = *reinterpret_cast<const short8*>(&lt[n][kp * 8]);
        char* dst = (char*)wb + (size_t)ng * 2048 + (k0 >> 6) * 128
                  + ((kp * 16) ^ ((ng & 7) << 4));
        *reinterpret_cast<short8*>(dst) = v;
    }
}

// ---------------- Kernel 1: QKV GEMM, BN=192, X read once, 8 waves ----------------
// 256 blocks (1/CU), 8 waves = 4 row-groups x 2 n-halves (2 waves/SIMD).
// W 24KB/step dbuf via global_load_lds; X triple-buffered loop-carried regs.
// Raw s_barrier with counted vmcnt(4): X(t+2) stays in flight across barrier.
#define LOADX(R0,R1,R2,R3,t) {                                        \
    const float* p_ = xrow + (t) * 64;                                \
    R0 = *reinterpret_cast<const float4*>(p_);                        \
    R1 = *reinterpret_cast<const float4*>(p_ + 4);                    \
    R2 = *reinterpret_cast<const float4*>(p_ + 32);                   \
    R3 = *reinterpret_cast<const float4*>(p_ + 36); }

#define STAGEW(buf, t) {                                              \
    _Pragma("unroll") for (int p_ = 0; p_ < 3; ++p_) {                \
        int c_ = p_ * 512 + tid;                                      \
        gl2lds16((const char*)wb + (size_t)(c_ >> 3) * 2048           \
                     + (size_t)(t) * 128 + (c_ & 7) * 16,             \
                 (char*)&Ws[buf][0] + c_ * 16);                       \
    } }

__global__ __launch_bounds__(512) void qkv_mm(
    const float* __restrict__ x, const unsigned short* __restrict__ wb,
    unsigned short* __restrict__ kb, unsigned short* __restrict__ qb,
    unsigned short* __restrict__ vT)
{
    __shared__ __align__(16) unsigned short Ws[2][192 * 64];   // 48 KB

    const int tid  = threadIdx.x;
    const int wid  = tid >> 6;          // 0..7
    const int rowg = wid & 3;
    const int nh   = wid >> 2;          // n-half: 0 or 1
    const int lane = tid & 63;
    const int lr   = lane & 15;
    const int lg   = lane >> 4;
    const int m0   = blockIdx.x * 64;

    const float* xrow = x + (size_t)(m0 + rowg * 16 + lr) * C_ + lg * 8;

    f32x4 acc[6];
    #pragma unroll
    for (int c = 0; c < 6; ++c) acc[c] = (f32x4){0.f, 0.f, 0.f, 0.f};

    float4 xA0, xA1, xA2, xA3, xB0, xB1, xB2, xB3, xC0, xC1, xC2, xC3;

    LOADX(xA0, xA1, xA2, xA3, 0);
    __builtin_amdgcn_sched_barrier(0);
    STAGEW(0, 0);
    __builtin_amdgcn_sched_barrier(0);
    LOADX(xB0, xB1, xB2, xB3, 1);
    __builtin_amdgcn_sched_barrier(0);

    #pragma unroll
    for (int t = 0; t < 16; ++t) {
        if (t < 15) asm volatile("s_waitcnt vmcnt(4) lgkmcnt(0)" ::: "memory");
        else        asm volatile("s_waitcnt vmcnt(0) lgkmcnt(0)" ::: "memory");
        __builtin_amdgcn_s_barrier();
        __builtin_amdgcn_sched_barrier(0);
        if (t < 15) { STAGEW((t + 1) & 1, t + 1); }
        __builtin_amdgcn_sched_barrier(0);
        if (t < 14) { LOADX(xC0, xC1, xC2, xC3, t + 2); }
        __builtin_amdgcn_sched_barrier(0);

        short8 af0, af1;
        af0[0] = (short)f2bf(xA0.x); af0[1] = (short)f2bf(xA0.y);
        af0[2] = (short)f2bf(xA0.z); af0[3] = (short)f2bf(xA0.w);
        af0[4] = (short)f2bf(xA1.x); af0[5] = (short)f2bf(xA1.y);
        af0[6] = (short)f2bf(xA1.z); af0[7] = (short)f2bf(xA1.w);
        af1[0] = (short)f2bf(xA2.x); af1[1] = (short)f2bf(xA2.y);
        af1[2] = (short)f2bf(xA2.z); af1[3] = (short)f2bf(xA2.w);
        af1[4] = (short)f2bf(xA3.x); af1[5] = (short)f2bf(xA3.y);
        af1[6] = (short)f2bf(xA3.z); af1[7] = (short)f2bf(xA3.w);

        const char* wbuf = (const char*)&Ws[t & 1][0];
        #pragma unroll
        for (int kc = 0; kc < 2; ++kc) {
            short8 afc = kc ? af1 : af0;
            #pragma unroll
            for (int ct = 0; ct < 6; ++ct) {
                int n = nh * 96 + ct * 16 + lr;
                short8 bf = *reinterpret_cast<const short8*>(
                    wbuf + n * 128 + ((kc * 64 + lg * 16) ^ ((n & 7) << 4)));
                acc[ct] = __builtin_amdgcn_mfma_f32_16x16x32_bf16(afc, bf, acc[ct], 0, 0, 0);
            }
        }
        xA0 = xB0; xA1 = xB1; xA2 = xB2; xA3 = xB3;
        xB0 = xC0; xB1 = xC1; xB2 = xC2; xB3 = xC3;
    }

    // epilogue: D layout col=lane&15, row=(lane>>4)*4+reg
    #pragma unroll
    for (int ct = 0; ct < 6; ++ct) {
        int n = nh * 96 + ct * 16 + lr;
        int col = n & 63;
        #pragma unroll
        for (int i = 0; i < 4; ++i) {
            int m = m0 + rowg * 16 + lg * 4 + i;
            unsigned short val = f2bf(acc[ct][i]);
            if (n < 64)       kb[(size_t)m * H_ + col] = val;
            else if (n < 128) qb[(size_t)m * H_ + col] = val;
            else              vT[((size_t)(m >> 11) * H_ + col) * T_ + (m & (T_ - 1))] = val;
        }
    }
}

// ---------------- Kernel 2: flash attention, shared-LDS 4-wave blocks, split-KV ----------------
// Block = 64-row q-tile (4 waves x 16 rows). Per step: stage K(8KB)+V(8KB) into
// shared dbuf LDS via global_load_lds (coalesced, source-preswizzled), raw
// s_barrier + vmcnt(0), all waves compute. Grid (4 splits, 32 tiles, 8 batches).
__global__ __launch_bounds__(256) void attn8(
    const unsigned short* __restrict__ kb,
    const unsigned short* __restrict__ qb,
    const unsigned short* __restrict__ vT,
    unsigned short* __restrict__ opart,
    float* __restrict__ ml)
{
    __shared__ __align__(16) char KV[2][16384];        // [buf][ K 8KB | V 8KB ]
    __shared__ __align__(16) unsigned short Ps[4][16][72];

    const int tid  = threadIdx.x;
    const int wid  = tid >> 6;
    const int lane = tid & 63;
    const int lr   = lane & 15;
    const int lg   = lane >> 4;
    const int s0   = blockIdx.x;                 // split 0..3
    const int tile = 31 - blockIdx.y;            // big q-tiles first
    const int b    = blockIdx.z;
    const int q0   = tile * 64;
    const int wq0  = q0 + wid * 16;
    const int nst  = tile + 1;                   // kv tiles of 64 needed
    const size_t base = (size_t)b * T_ * H_;
    const char* kbyte = (const char*)(kb + base);
    const char* vbyte = (const char*)(vT + (size_t)b * H_ * T_);

    auto STAGE = [&](int buf, int kv0) {
        char* kd = KV[buf];
        const char* ks = kbyte + (size_t)kv0 * 128;
        const char* vs = vbyte + (size_t)kv0 * 2;
        #pragma unroll
        for (int i = 0; i < 2; ++i) {
            int c = i * 256 + tid;               // 0..511
            int row = c >> 3, colB = (c & 7) * 16;
            gl2lds16(ks + row * 128 + (colB ^ ((row & 7) << 4)), kd + c * 16);
        }
        #pragma unroll
        for (int i = 0; i < 2; ++i) {
            int c = i * 256 + tid;
            int row = c >> 3, colB = (c & 7) * 16;
            gl2lds16(vs + (size_t)row * 4096 + (colB ^ ((row & 7) << 4)),
                     kd + 8192 + c * 16);
        }
    };

    short8 qf[2];
    #pragma unroll
    for (int kc = 0; kc < 2; ++kc)
        qf[kc] = *reinterpret_cast<const short8*>(
            qb + base + (size_t)(wq0 + lr) * H_ + kc * 32 + lg * 8);

    f32x4 o[4];
    float mrun[4], lrun[4];
    for (int dt = 0; dt < 4; ++dt) o[dt] = (f32x4){0.f, 0.f, 0.f, 0.f};
    for (int i = 0; i < 4; ++i) { mrun[i] = -INFINITY; lrun[i] = 0.f; }

    int cur = 0;
    if (s0 < nst) STAGE(0, s0 * 64);

    for (int s = s0; s < nst; s += 4) {
        const int kv0 = s * 64;
        const bool more = (s + 4) < nst;

        asm volatile("s_waitcnt vmcnt(0)" ::: "memory");
        __builtin_amdgcn_s_barrier();           // stage(s) visible; prev buf free
        __builtin_amdgcn_sched_barrier(0);
        if (more) STAGE(cur ^ 1, kv0 + 256);    // in flight under compute

        // S = Q K^T from swizzled shared K tile
        const char* kt_base = KV[cur];
        f32x4 sv4[4];
        #pragma unroll
        for (int kt = 0; kt < 4; ++kt) sv4[kt] = (f32x4){0.f, 0.f, 0.f, 0.f};
        #pragma unroll
        for (int kc = 0; kc < 2; ++kc) {
            #pragma unroll
            for (int kt = 0; kt < 4; ++kt) {
                int row = kt * 16 + lr;
                short8 kf = *reinterpret_cast<const short8*>(
                    kt_base + row * 128 + ((kc * 64 + lg * 16) ^ ((row & 7) << 4)));
                sv4[kt] = __builtin_amdgcn_mfma_f32_16x16x32_bf16(qf[kc], kf, sv4[kt], 0, 0, 0);
            }
        }

        const bool need_mask = (s == tile);      // diagonal 64x64 tile
        #pragma unroll
        for (int i = 0; i < 4; ++i) {
            int row = wq0 + lg * 4 + i;
            float sv[4];
            float mx = -INFINITY;
            if (need_mask) {
                #pragma unroll
                for (int kt = 0; kt < 4; ++kt) {
                    int key = kv0 + kt * 16 + lr;
                    float v = (key <= row) ? sv4[kt][i] : -INFINITY;
                    sv[kt] = v;
                    mx = fmaxf(mx, v);
                }
            } else {
                #pragma unroll
                for (int kt = 0; kt < 4; ++kt) {
                    sv[kt] = sv4[kt][i];
                    mx = fmaxf(mx, sv[kt]);
                }
            }
            for (int d = 8; d; d >>= 1) mx = fmaxf(mx, __shfl_xor(mx, d));
            float mn  = fmaxf(mrun[i], mx);
            float fac = __expf(mrun[i] - mn);
            float rs  = 0.f;
            #pragma unroll
            for (int kt = 0; kt < 4; ++kt) {
                float p = __expf(sv[kt] - mn);
                rs += p;
                Ps[wid][lg * 4 + i][kt * 16 + lr] = f2bf(p);
            }
            for (int d = 8; d; d >>= 1) rs += __shfl_xor(rs, d);
            lrun[i] = lrun[i] * fac + rs;
            mrun[i] = mn;
            #pragma unroll
            for (int dt = 0; dt < 4; ++dt)
                o[dt][i] *= fac;
        }

        // O += P * V from swizzled shared V tile
        const char* vt_base = KV[cur] + 8192;
        #pragma unroll
        for (int kc = 0; kc < 2; ++kc) {
            short8 pf = *reinterpret_cast<const short8*>(&Ps[wid][lr][kc * 32 + lg * 8]);
            #pragma unroll
            for (int dt = 0; dt < 4; ++dt) {
                int row = dt * 16 + lr;
                short8 vf = *reinterpret_cast<const short8*>(
                    vt_base + row * 128 + ((kc * 64 + lg * 16) ^ ((row & 7) << 4)));
                o[dt] = __builtin_amdgcn_mfma_f32_16x16x32_bf16(pf, vf, o[dt], 0, 0, 0);
            }
        }
        cur ^= 1;
    }

    // write partials (always; merge reads all 4 splits)
    unsigned short* op = opart + ((size_t)s0 * M_ + (size_t)b * T_ + wq0) * H_;
    #pragma unroll
    for (int i = 0; i < 4; ++i)
        #pragma unroll
        for (int dt = 0; dt < 4; ++dt)
            op[(size_t)(lg * 4 + i) * H_ + dt * 16 + lr] = f2bf(o[dt][i]);
    if (lr == 0) {
        float* mlp = ml + ((size_t)s0 * M_ + (size_t)b * T_ + wq0) * 2;
        #pragma unroll
        for (int i = 0; i < 4; ++i) {
            mlp[(lg * 4 + i) * 2 + 0] = mrun[i];
            mlp[(lg * 4 + i) * 2 + 1] = lrun[i];
        }
    }
}

// ---------------- Kernel 3: merge 4 split-KV partials ----------------
__global__ __launch_bounds__(256) void attn_merge(
    const unsigned short* __restrict__ opart,
    const float* __restrict__ ml,
    float* __restrict__ out)
{
    const int idx = blockIdx.x * 256 + threadIdx.x;   // 0..1048575
    const int row = idx >> 6;
    const int col = idx & 63;

    float mv[4], lv[4];
    float M = -INFINITY;
    #pragma unroll
    for (int s = 0; s < 4; ++s) {
        mv[s] = ml[((size_t)s * M_ + row) * 2 + 0];
        lv[s] = ml[((size_t)s * M_ + row) * 2 + 1];
        M = fmaxf(M, mv[s]);
    }
    float L = 0.f, acc = 0.f;
    #pragma unroll
    for (int s = 0; s < 4; ++s) {
        float fac = __expf(mv[s] - M);
        L += lv[s] * fac;
        acc += bf2f(opart[(size_t)s * M_ * H_ + (size_t)row * H_ + col]) * fac;
    }
    out[idx] = acc / L;
}

extern "C" void kernel_launch(void* const* d_in, const int* in_sizes, int n_in,
                              void* d_out, int out_size, void* d_ws, size_t ws_size,
                              hipStream_t stream) {
    const float* x  = (const float*)d_in[0];
    const float* Wk = (const float*)d_in[1];
    const float* Wq = (const float*)d_in[2];
    const float* Wv = (const float*)d_in[3];
    float* out = (float*)d_out;

    unsigned short* kb    = (unsigned short*)d_ws;           // 2 MB
    unsigned short* qb    = kb + (size_t)M_ * H_;            // 2 MB
    unsigned short* vT    = qb + (size_t)M_ * H_;            // 2 MB ([b][d][t])
    unsigned short* wb    = vT + (size_t)M_ * H_;            // 384 KB
    unsigned short* opart = wb + (size_t)192 * C_;           // 8 MB
    float*          ml    = (float*)(opart + (size_t)4 * M_ * H_);  // 512 KB

    wconv<<<48, 256, 0, stream>>>(Wk, Wq, Wv, wb);
    qkv_mm<<<256, 512, 0, stream>>>(x, wb, kb, qb, vT);
    attn8<<<dim3(4, 32, B_), 256, 0, stream>>>(kb, qb, vT, opart, ml);
    attn_merge<<<M_ * H_ / 256, 256, 0, stream>>>(opart, ml, out);
}